// Round 6
// baseline (340.217 us; speedup 1.0000x reference)
//
#include <hip/hip_runtime.h>

#define NIN   55296
#define CIN   256
#define COUT  256
#define NTH   512
#define NBLK  432   // 2 parities * 216 tiles of 256 rows

typedef __attribute__((ext_vector_type(8))) _Float16 half8;
typedef __attribute__((ext_vector_type(4))) _Float16 half4;
typedef __attribute__((ext_vector_type(4))) float f32x4;

typedef const __attribute__((address_space(1))) void* gp_t;
typedef __attribute__((address_space(3))) void* lp_t;
__device__ __forceinline__ void gload16(const void* g, char* l) {
  __builtin_amdgcn_global_load_lds((gp_t)g, (lp_t)l, 16, 0, 0);
}

// ---------- pre-pass: features f32 -> f16 ----------
__global__ void k_feat_cvt(const float* __restrict__ f, _Float16* __restrict__ o, int n4) {
  int i = blockIdx.x * blockDim.x + threadIdx.x;
  if (i >= n4) return;
  f32x4 v = ((const f32x4*)f)[i];
  half4 r;
  r[0] = (_Float16)v[0]; r[1] = (_Float16)v[1];
  r[2] = (_Float16)v[2]; r[3] = (_Float16)v[3];
  ((half4*)o)[i] = r;
}

// ---------- pre-pass: W f32 [27][cin][cout] -> f16 transposed Wt [27][cout][cin]
__global__ void k_w_cvt(const float* __restrict__ W, _Float16* __restrict__ Wt,
                        float* __restrict__ zeros) {
  int i = blockIdx.x * blockDim.x + threadIdx.x;
  int d   = i >> 16;
  int rem = i & 65535;
  int n   = rem >> 8;
  int k   = rem & 255;
  Wt[i] = (_Float16)W[(d << 16) + (k << 8) + n];
  if (blockIdx.x == 0 && threadIdx.x < 128) zeros[threadIdx.x] = 0.0f;
}

// ---------- main: 8-wave 256x256 tile, BK=64 ----------
// A: dbuf LDS (2 x 32KB, DMA via global_load_lds, XOR-swizzled).  B: global->VGPR
// per step, SINGLE-buffered (8 x dwordx4 from L2-resident Wt; issued BEFORE the
// next-step DMA so the counted vmcnt wait for b[0] never drains the DMA queue).
// LDS half d at d*32768: A_ks0 @+0 (256 rows x 64B), A_ks1 @+16384. orow @65536.
// Per step: __syncthreads -> b loads (cur) -> DMA A (next) -> a ds_reads -> 4 MFMA phases
// (P1 rolls a[mf] reload to ksub1 after last ksub0 use).
__global__ __launch_bounds__(NTH, 2)
void k_conv8(const _Float16* __restrict__ featb, const _Float16* __restrict__ wt,
             const char* __restrict__ zeros, float* __restrict__ out) {
  extern __shared__ char lds[];
  int* orow = (int*)(lds + 65536);

  const int braw = blockIdx.x;
  const int b    = (braw & 7) * 54 + (braw >> 3);   // bijective XCD swizzle (432 = 8*54)
  const int p    = b & 1;                            // output-voxel parity
  const int tile = b >> 1;                           // 0..215

  const int tid = threadIdx.x;
  const int w   = tid >> 6;
  const int l   = tid & 63;

  // ---- A staging geometry: thread stages rows R0=rr, R1=128+rr; 4 lanes/row, 16B slots
  const int rr  = w * 16 + (l >> 2);                 // [0,128)
  const int swz = ((l & 3) ^ ((l >> 3) & 3)) * 16;   // slot XOR swizzle (key=((row&15)>>1)&3)

  int xs[2], ys[2], zs[2];
#pragma unroll
  for (int q = 0; q < 2; ++q) {
    int e = tile * 256 + q * 128 + rr;
    int c = e / 24;
    int zi = e - c * 24;
    int x = c / 48;
    int y = c - x * 48;
    xs[q] = x; ys[q] = y; zs[q] = 2 * zi + ((x + y + p) & 1);
  }
  const char* wtc   = (const char*)wt;
  const char* featc = (const char*)featb;

  // ---- fragment geometry ----
  const int wm = w >> 2, wn = w & 3;
  const int lr = l & 15, kg = l >> 4;
  const int rsw = (kg ^ ((lr >> 1) & 3)) * 16;       // read-side swizzle (matches store)
  const int aRd = (wm * 128 + lr) * 64 + rsw;
  const int bq  = (wn * 64 + lr) * 512 + kg * 16;    // B global lane offset

  // ---- orow table (visible after first __syncthreads) ----
  if (tid < 256) {
    int e = tile * 256 + tid;
    int c = e / 24;
    int zi = e - c * 24;
    int x = c / 48;
    int y = c - x * 48;
    int z = 2 * zi + ((x + y + p) & 1);
    orow[tid] = (x * 48 + y) * 48 + z;
  }

  // ---- A-gather offset state (prefetch side: offset of step s+1) ----
  const char* asrc[2];
  auto setoff = [&](int d27) {
    int dx = d27 / 9 - 1, dy = (d27 / 3) % 3 - 1, dz = d27 % 3 - 1;
#pragma unroll
    for (int q = 0; q < 2; ++q) {
      int ux = xs[q] + dx, uy = ys[q] + dy, uz = zs[q] + dz;
      bool v = (unsigned)ux < 48u && (unsigned)uy < 48u && (unsigned)uz < 48u;
      int idx = (ux * 48 + uy) * 24 + (uz >> 1);     // analytic even-lattice row id
      asrc[q] = (v ? (featc + idx * 512) : zeros) + swz;
    }
  };

  const int pb = p ? 0 : 1;                          // first offset with sum-parity p
  int pn = pb;
  setoff(pn);

  // ---- prologue: stage A K-step 0 into half 0 (4 gloads) ----
  gload16(asrc[0],      lds + 0     + w * 1024);
  gload16(asrc[1],      lds + 8192  + w * 1024);
  gload16(asrc[0] + 64, lds + 16384 + w * 1024);
  gload16(asrc[1] + 64, lds + 24576 + w * 1024);

  f32x4 acc[8][4];
#pragma unroll
  for (int i = 0; i < 8; ++i)
#pragma unroll
    for (int j = 0; j < 4; ++j) acc[i][j] = (f32x4)0.0f;

  const int S = p ? 56 : 52;                         // (14 or 13 offsets) * 4 K-steps

  for (int s = 0; s < S; ++s) {
    __syncthreads();   // vmcnt(0): A-DMA into half d landed; d^1 readers done

    const char* Ab = lds + (s & 1) * 32768;

    // ---- B loads for CURRENT step (global->VGPR, L2-hot Wt) — issued FIRST ----
    const char* wk = wtc + (pb + ((s >> 2) << 1)) * 131072 + (s & 3) * 128 + bq;
    half8 bf[8];
    bf[0] = *(const half8*)(wk);             // nf0 ks0
    bf[1] = *(const half8*)(wk + 8192);      // nf1 ks0
    bf[2] = *(const half8*)(wk + 16384);     // nf2 ks0
    bf[3] = *(const half8*)(wk + 24576);     // nf3 ks0
    bf[4] = *(const half8*)(wk + 64);        // nf0 ks1
    bf[5] = *(const half8*)(wk + 8256);      // nf1 ks1
    bf[6] = *(const half8*)(wk + 16448);     // nf2 ks1
    bf[7] = *(const half8*)(wk + 24640);     // nf3 ks1
    __builtin_amdgcn_sched_barrier(0);

    // ---- A-DMA for NEXT step (younger in vmem queue than b loads) ----
    const int sn = s + 1;
    if (sn < S) {
      if ((sn & 3) == 0) { pn += 2; setoff(pn); }
      char* Nb = lds + (sn & 1) * 32768;
      const int kb = (sn & 3) * 128;
      gload16(asrc[0] + kb,      Nb + 0     + w * 1024);
      gload16(asrc[1] + kb,      Nb + 8192  + w * 1024);
      gload16(asrc[0] + kb + 64, Nb + 16384 + w * 1024);
      gload16(asrc[1] + kb + 64, Nb + 24576 + w * 1024);
    }
    __builtin_amdgcn_sched_barrier(0);

    // ---- A ksub0 fragments ----
    half8 a[8];
#pragma unroll
    for (int mf = 0; mf < 8; ++mf) a[mf] = *(const half8*)(Ab + aRd + mf * 1024);
    __builtin_amdgcn_sched_barrier(0);

    // ---- P0: ksub0 x nf{0,1} ----
    __builtin_amdgcn_s_setprio(1);
#pragma unroll
    for (int mf = 0; mf < 8; ++mf) {
      acc[mf][0] = __builtin_amdgcn_mfma_f32_16x16x32_f16(a[mf], bf[0], acc[mf][0], 0, 0, 0);
      acc[mf][1] = __builtin_amdgcn_mfma_f32_16x16x32_f16(a[mf], bf[1], acc[mf][1], 0, 0, 0);
    }
    __builtin_amdgcn_s_setprio(0);
    __builtin_amdgcn_sched_barrier(0);

    // ---- P1: ksub0 x nf{2,3}, rolling reload a[mf] <- ksub1 after last use ----
    __builtin_amdgcn_s_setprio(1);
#pragma unroll
    for (int mf = 0; mf < 8; ++mf) {
      acc[mf][2] = __builtin_amdgcn_mfma_f32_16x16x32_f16(a[mf], bf[2], acc[mf][2], 0, 0, 0);
      acc[mf][3] = __builtin_amdgcn_mfma_f32_16x16x32_f16(a[mf], bf[3], acc[mf][3], 0, 0, 0);
      a[mf] = *(const half8*)(Ab + 16384 + aRd + mf * 1024);
    }
    __builtin_amdgcn_s_setprio(0);
    __builtin_amdgcn_sched_barrier(0);

    // ---- P2: ksub1 x nf{0,1} ----
    __builtin_amdgcn_s_setprio(1);
#pragma unroll
    for (int mf = 0; mf < 8; ++mf) {
      acc[mf][0] = __builtin_amdgcn_mfma_f32_16x16x32_f16(a[mf], bf[4], acc[mf][0], 0, 0, 0);
      acc[mf][1] = __builtin_amdgcn_mfma_f32_16x16x32_f16(a[mf], bf[5], acc[mf][1], 0, 0, 0);
    }
    __builtin_amdgcn_s_setprio(0);
    __builtin_amdgcn_sched_barrier(0);

    // ---- P3: ksub1 x nf{2,3} ----
    __builtin_amdgcn_s_setprio(1);
#pragma unroll
    for (int mf = 0; mf < 8; ++mf) {
      acc[mf][2] = __builtin_amdgcn_mfma_f32_16x16x32_f16(a[mf], bf[6], acc[mf][2], 0, 0, 0);
      acc[mf][3] = __builtin_amdgcn_mfma_f32_16x16x32_f16(a[mf], bf[7], acc[mf][3], 0, 0, 0);
    }
    __builtin_amdgcn_s_setprio(0);
  }

  // ---- epilogue: C/D layout col=lane&15, row=(lane>>4)*4+i ----
#pragma unroll
  for (int mf = 0; mf < 8; ++mf) {
#pragma unroll
    for (int i = 0; i < 4; ++i) {
      int r = wm * 128 + mf * 16 + kg * 4 + i;
      int o = orow[r];
      float* dst = out + (size_t)o * COUT + wn * 64 + lr;
#pragma unroll
      for (int nf = 0; nf < 4; ++nf) dst[nf * 16] = acc[mf][nf][i];
    }
  }
}

extern "C" void kernel_launch(void* const* d_in, const int* in_sizes, int n_in,
                              void* d_out, int out_size, void* d_ws, size_t ws_size,
                              hipStream_t stream) {
  const float* features = (const float*)d_in[0];
  const float* W = (const float*)d_in[3];
  float* out = (float*)d_out;

  char* ws = (char*)d_ws;
  _Float16* featb = (_Float16*)ws;                      // 28,311,552 B
  _Float16* Wt    = (_Float16*)(ws + 28311552);         //  3,538,944 B
  float*    zeros = (float*)(ws + 28311552 + 3538944);  //       512 B

  (void)hipFuncSetAttribute(reinterpret_cast<const void*>(k_conv8),
                            hipFuncAttributeMaxDynamicSharedMemorySize, 66560);

  {
    int n4 = NIN * CIN / 4;
    k_feat_cvt<<<(n4 + 255) / 256, 256, 0, stream>>>(features, featb, n4);
  }
  k_w_cvt<<<27 * 65536 / 256, 256, 0, stream>>>(W, Wt, zeros);

  k_conv8<<<NBLK, NTH, 66560, stream>>>(featb, Wt, (const char*)zeros, out);
}

// Round 7
// 225.262 us; speedup vs baseline: 1.5103x; 1.5103x over previous
//
#include <hip/hip_runtime.h>

#define NIN   55296
#define CIN   256
#define COUT  256
#define NTH   512
#define NBLK  432   // 2 parities * 216 tiles of 256 rows

typedef __attribute__((ext_vector_type(8))) _Float16 half8;
typedef __attribute__((ext_vector_type(4))) _Float16 half4;
typedef __attribute__((ext_vector_type(4))) float f32x4;

typedef const __attribute__((address_space(1))) void* gp_t;
typedef __attribute__((address_space(3))) void* lp_t;
__device__ __forceinline__ void gload16(const void* g, char* l) {
  __builtin_amdgcn_global_load_lds((gp_t)g, (lp_t)l, 16, 0, 0);
}

// ---------- pre-pass: features f32 -> f16 ----------
__global__ void k_feat_cvt(const float* __restrict__ f, _Float16* __restrict__ o, int n4) {
  int i = blockIdx.x * blockDim.x + threadIdx.x;
  if (i >= n4) return;
  f32x4 v = ((const f32x4*)f)[i];
  half4 r;
  r[0] = (_Float16)v[0]; r[1] = (_Float16)v[1];
  r[2] = (_Float16)v[2]; r[3] = (_Float16)v[3];
  ((half4*)o)[i] = r;
}

// ---------- pre-pass: W f32 [27][cin][cout] -> f16 transposed Wt [27][cout][cin]
__global__ void k_w_cvt(const float* __restrict__ W, _Float16* __restrict__ Wt,
                        float* __restrict__ zeros) {
  int i = blockIdx.x * blockDim.x + threadIdx.x;
  int d   = i >> 16;
  int rem = i & 65535;
  int n   = rem >> 8;
  int k   = rem & 255;
  Wt[i] = (_Float16)W[(d << 16) + (k << 8) + n];
  if (blockIdx.x == 0 && threadIdx.x < 128) zeros[threadIdx.x] = 0.0f;
}

// ---------- main: 8-wave 256x256 tile, BK=32, 4-deep LDS pipeline ----------
// Buffer i (i = step & 3) at lds + i*32768: A [256 rows][64B] @+0, B [256 couts][64B] @+16384.
// Per wave per step: 4 gloads (A q0,q1 + B q0,q1) issued for step s+2.
// Barrier protocol (T3/T4): s_waitcnt vmcnt(4) (own step-s loads landed, step-s+1's
// 4 still in flight) -> raw s_barrier -> issue s+2 -> 12 ds_reads + 32 MFMA
// (compiler's counted lgkmcnt interleaves reads under MFMA). vmcnt(0) only at tail.
// WAR: writes at step s target buf (s+2)&3, whose readers (step s-2) finished
// before barrier s-1; barrier order makes this safe for all waves.
__global__ __launch_bounds__(NTH, 2)
void k_conv8(const _Float16* __restrict__ featb, const _Float16* __restrict__ wt,
             const char* __restrict__ zeros, float* __restrict__ out) {
  extern __shared__ char lds[];
  int* orow = (int*)(lds + 131072);

  const int braw = blockIdx.x;
  const int b    = (braw & 7) * 54 + (braw >> 3);   // bijective XCD swizzle (432 = 8*54)
  const int p    = b & 1;                            // output-voxel parity
  const int tile = b >> 1;                           // 0..215

  const int tid = threadIdx.x;
  const int w   = tid >> 6;
  const int l   = tid & 63;

  // ---- staging geometry: wave w stages rows [w*32, w*32+32) of A and of B(couts).
  // gload q covers rows w*32+q*16 .. +16; lane l -> row +(l>>2), 16B slot (l&3), swizzled.
  const int swz  = ((l & 3) ^ ((l >> 3) & 3)) * 16;  // slot XOR key = (localrow>>1)&3
  const int stA0 = w * 2048;                          // 32 rows * 64B

  int xs[2], ys[2], zs[2];
#pragma unroll
  for (int q = 0; q < 2; ++q) {
    int e  = tile * 256 + w * 32 + q * 16 + (l >> 2);
    int c  = e / 24;
    int zi = e - c * 24;
    int x  = c / 48;
    int y  = c - x * 48;
    xs[q] = x; ys[q] = y; zs[q] = 2 * zi + ((x + y + p) & 1);
  }
  const char* wtc   = (const char*)wt;
  const char* featc = (const char*)featb;
  const int brow0 = (w * 32 + (l >> 2)) * 512 + swz;       // Wt row byte offsets
  const int brow1 = (w * 32 + 16 + (l >> 2)) * 512 + swz;

  // ---- fragment-read geometry (K=32 per step: one 16x16x32 ksub) ----
  const int wm = w >> 2, wn = w & 3;
  const int lr = l & 15, kg = l >> 4;
  const int rsw = (kg ^ ((lr >> 1) & 3)) * 16;       // read-side swizzle (matches store)
  const int aRd = (wm * 128 + lr) * 64 + rsw;
  const int bRd = 16384 + (wn * 64 + lr) * 64 + rsw;

  // ---- orow table ----
  if (tid < 256) {
    int e = tile * 256 + tid;
    int c = e / 24;
    int zi = e - c * 24;
    int x = c / 48;
    int y = c - x * 48;
    int z = 2 * zi + ((x + y + p) & 1);
    orow[tid] = (x * 48 + y) * 48 + z;
  }
  asm volatile("s_waitcnt lgkmcnt(0)" ::: "memory");  // orow visible before raw barriers
  __builtin_amdgcn_s_barrier();

  // ---- offset state (prefetch side) ----
  const char* asrc[2];
  const char* wtile;
  auto setoff = [&](int d27) {
    int dx = d27 / 9 - 1, dy = (d27 / 3) % 3 - 1, dz = d27 % 3 - 1;
#pragma unroll
    for (int q = 0; q < 2; ++q) {
      int ux = xs[q] + dx, uy = ys[q] + dy, uz = zs[q] + dz;
      bool v = (unsigned)ux < 48u && (unsigned)uy < 48u && (unsigned)uz < 48u;
      int idx = (ux * 48 + uy) * 24 + (uz >> 1);     // analytic even-lattice row id
      asrc[q] = (v ? (featc + idx * 512) : zeros) + swz;
    }
    wtile = wtc + d27 * 131072;
  };

  const int pb = p ? 0 : 1;                          // first offset with sum-parity p
  setoff(pb);

  // ---- prologue: issue steps 0 (buf0, kb=0) and 1 (buf1, kb=64) ----
  gload16(asrc[0],           lds + stA0);
  gload16(asrc[1],           lds + stA0 + 1024);
  gload16(wtile + brow0,     lds + 16384 + stA0);
  gload16(wtile + brow1,     lds + 16384 + stA0 + 1024);
  gload16(asrc[0] + 64,      lds + 32768 + stA0);
  gload16(asrc[1] + 64,      lds + 32768 + stA0 + 1024);
  gload16(wtile + brow0 + 64, lds + 32768 + 16384 + stA0);
  gload16(wtile + brow1 + 64, lds + 32768 + 16384 + stA0 + 1024);

  f32x4 acc[8][4];
#pragma unroll
  for (int i = 0; i < 8; ++i)
#pragma unroll
    for (int j = 0; j < 4; ++j) acc[i][j] = (f32x4)0.0f;

  const int S = p ? 112 : 104;                       // (14 or 13 offsets) * 8 K-steps

  for (int s = 0; s < S; ++s) {
    // counted wait: this step's 4 loads landed; next step's 4 stay in flight
    if (s + 1 < S) asm volatile("s_waitcnt vmcnt(4)" ::: "memory");
    else           asm volatile("s_waitcnt vmcnt(0)" ::: "memory");
    __builtin_amdgcn_s_barrier();
    __builtin_amdgcn_sched_barrier(0);

    // ---- issue staging for step s+2 into buf (s+2)&3 ----
    const int s2 = s + 2;
    if (s2 < S) {
      if ((s2 & 7) == 0) setoff(pb + ((s2 >> 3) << 1));
      const int kb = (s2 & 7) * 64;
      char* Nb = lds + (s2 & 3) * 32768;
      gload16(asrc[0] + kb,           Nb + stA0);
      gload16(asrc[1] + kb,           Nb + stA0 + 1024);
      gload16(wtile + brow0 + kb,     Nb + 16384 + stA0);
      gload16(wtile + brow1 + kb,     Nb + 16384 + stA0 + 1024);
    }
    __builtin_amdgcn_sched_barrier(0);

    // ---- 12 ds_reads + 32 MFMA (counted lgkm: reads drain under MFMA) ----
    const char* Ab = lds + (s & 3) * 32768;
    half8 a[8], bf[4];
#pragma unroll
    for (int nf = 0; nf < 4; ++nf) bf[nf] = *(const half8*)(Ab + bRd + nf * 1024);
#pragma unroll
    for (int mf = 0; mf < 8; ++mf) a[mf] = *(const half8*)(Ab + aRd + mf * 1024);

    __builtin_amdgcn_s_setprio(1);
#pragma unroll
    for (int mf = 0; mf < 8; ++mf)
#pragma unroll
      for (int nf = 0; nf < 4; ++nf)
        acc[mf][nf] = __builtin_amdgcn_mfma_f32_16x16x32_f16(a[mf], bf[nf], acc[mf][nf], 0, 0, 0);
    __builtin_amdgcn_s_setprio(0);
  }

  // ---- epilogue: C/D layout col=lane&15, row=(lane>>4)*4+i ----
#pragma unroll
  for (int mf = 0; mf < 8; ++mf) {
#pragma unroll
    for (int i = 0; i < 4; ++i) {
      int r = wm * 128 + mf * 16 + kg * 4 + i;
      int o = orow[r];
      float* dst = out + (size_t)o * COUT + wn * 64 + lr;
#pragma unroll
      for (int nf = 0; nf < 4; ++nf) dst[nf * 16] = acc[mf][nf][i];
    }
  }
}

extern "C" void kernel_launch(void* const* d_in, const int* in_sizes, int n_in,
                              void* d_out, int out_size, void* d_ws, size_t ws_size,
                              hipStream_t stream) {
  const float* features = (const float*)d_in[0];
  const float* W = (const float*)d_in[3];
  float* out = (float*)d_out;

  char* ws = (char*)d_ws;
  _Float16* featb = (_Float16*)ws;                      // 28,311,552 B
  _Float16* Wt    = (_Float16*)(ws + 28311552);         //  3,538,944 B
  float*    zeros = (float*)(ws + 28311552 + 3538944);  //       512 B

  (void)hipFuncSetAttribute(reinterpret_cast<const void*>(k_conv8),
                            hipFuncAttributeMaxDynamicSharedMemorySize, 132096);

  {
    int n4 = NIN * CIN / 4;
    k_feat_cvt<<<(n4 + 255) / 256, 256, 0, stream>>>(features, featb, n4);
  }
  k_w_cvt<<<27 * 65536 / 256, 256, 0, stream>>>(W, Wt, zeros);

  k_conv8<<<NBLK, NTH, 132096, stream>>>(featb, Wt, (const char*)zeros, out);
}